// Round 12
// baseline (252.314 us; speedup 1.0000x reference)
//
#include <hip/hip_runtime.h>

// ---------------------------------------------------------------------------
// sxsGCN: h=[B=128,N=4096,3]; 3x { relu((adj@h)@W+b) }; then FC 12288->54->4096
// bf16 MFMA GEMMs adj[4096x4096] @ H[4096 x 512].
// R13: barrier-free GEMM, both operands frag-packed global->VGPR.
// R14: fc1 fused into gcn<2>: 218us. R17: 8-way k-slice 512-thr (4 waves/
//   SIMD): 209us.
// R18/R19: 128x64 tile, 1024 thr: VGPR_Count=64 BOTH with lb(1024,4) and
//   plain lb(1024) -- backend default for 1024-thr workgroups targets
//   8 waves/EU (2 blocks/CU) => VGPR cap 64 => acc[4][4] spills (81MB
//   scratch writes/dispatch, 75us/gemm). Structure passed correctness twice;
//   the byte-cut experiment never actually ran unspilled.
// R20: pin occupancy with amdgpu_waves_per_eu(4,4): exactly 4 waves/EU ->
//   VGPR budget 128; demand ~116 fits, no spill. Otherwise byte-identical
//   to R19: 128x64 tile, 16 waves (2 m-halves x 8 k-slices), 1.5MB/CU
//   read-once, half-by-half R17-style reduce, fused fc1 tree.
// ---------------------------------------------------------------------------

typedef __bf16 bf16x8 __attribute__((ext_vector_type(8)));
typedef float  f32x4  __attribute__((ext_vector_type(4)));

#define N_NODE 4096
#define BATCH  128

// prep: [0,8192) adjB A-frag pack | [8192,9216) G0 B-frag pack = (X@W1)
//       | [9216,9243) zero hid
__global__ __launch_bounds__(256) void prep_k(const float* __restrict__ adj,
                                              __bf16* __restrict__ adjB,
                                              const float* __restrict__ X,
                                              const float* __restrict__ W1,
                                              __bf16* __restrict__ G0,
                                              float* __restrict__ hid_acc) {
    const int blk = blockIdx.x, tx = threadIdx.x;
    if (blk < 8192) {
        // A-frag pack: chunk g = (rb*128 + ka)*64 + lane holds
        // row = rb*16+(lane&15), k = ka*32+((lane>>4)&3)*8 .. +7
        const int g = blk * 256 + tx;
        const int lane = g & 63, ka = (g >> 6) & 127, rb = g >> 13;
        const int row = rb * 16 + (lane & 15);
        const int kb  = ka * 32 + ((lane >> 4) & 3) * 8;
        const float4* s = (const float4*)(adj + (size_t)row * 4096 + kb);
        float4 u = s[0];
        float4 v = s[1];
        bf16x8 o = { (__bf16)u.x, (__bf16)u.y, (__bf16)u.z, (__bf16)u.w,
                     (__bf16)v.x, (__bf16)v.y, (__bf16)v.z, (__bf16)v.w };
        *(bf16x8*)(adjB + (size_t)g * 8) = o;
    } else if (blk < 9216) {
        // B-frag pack: chunk g = (kc*32 + cb)*64 + lane holds
        // c = cb*16+(lane&15), m = kc*32+((lane>>4)&3)*8 .. +7
        const int g = (blk - 8192) * 256 + tx;
        const int lp = g & 63, cbg = (g >> 6) & 31, kc = g >> 11;
        const int c = cbg * 16 + (lp & 15);
        const int b = c >> 2, f = c & 3;
        const float w0 = W1[0 * 4 + f], w1 = W1[1 * 4 + f], w2 = W1[2 * 4 + f];
        const int mb = kc * 32 + ((lp >> 4) & 3) * 8;
        const float* Xb = X + (size_t)b * 12288 + (size_t)mb * 3;
        bf16x8 o;
#pragma unroll
        for (int j = 0; j < 8; ++j) {
            const float v = Xb[j * 3 + 0] * w0 + Xb[j * 3 + 1] * w1 + Xb[j * 3 + 2] * w2;
            o[j] = (__bf16)v;
        }
        *(bf16x8*)(G0 + (size_t)g * 8) = o;
    } else {
        const int i = (blk - 9216) * 256 + tx;
        if (i < BATCH * 54) hid_acc[i] = 0.f;
    }
}

// Fused GEMM + epilogue. Tile 128(M)x64(N), 1024 threads = 16 waves:
// wm = wave>>3 owns rows [wm*64,+64), wk = wave&7 owns k-chunks ka=kt*8+wk
// (16 steps), acc[4][4]. Both operands direct global->VGPR, frag-packed;
// no LDS/barriers in K-loop. Epilogue per half h (sequential): R17's 4-round
// 8-slot reduce -> Ct[64][66] -> MODE output for that half.
//   MODE 0: relu(C+b1) -> packed bf16       MODE 1: (relu(C@W2+b2))@W3 packed
//   MODE 2: fused fc1: hid[b][j] += sum_{n,f} relu(C+b3)*Wfc (atomicAdd)
template <int MODE>
__global__ __launch_bounds__(1024)
__attribute__((amdgpu_waves_per_eu(4, 4)))      // pin 4 waves/EU -> 128 VGPR
void gcn_k(const __bf16* __restrict__ A,
           const __bf16* __restrict__ Bp,
           const float* __restrict__ Wa,
           const float* __restrict__ ba,
           const float* __restrict__ Wb,
           __bf16* __restrict__ Op,
           float* __restrict__ hidOut) {
    __shared__ __align__(16) unsigned char smem[49664];
    const int tx = threadIdx.x;
    const int wave = tx >> 6, lane = tx & 63;
    const int wm = wave >> 3, wk = wave & 7;
    const int quad = lane >> 4, lr = lane & 15;

    const int l = blockIdx.x;
    const int xcd = l & 7, s = l >> 3;
    const int mi = xcd * 4 + (s & 3), ci = s >> 2;     // mi 0..31, ci 0..7
    const int m0 = mi * 128;

    // A frags: chunk (rb = mi*8 + wm*4 + i, ka = kt*8+wk)
    const __bf16* pA[4];
#pragma unroll
    for (int i = 0; i < 4; ++i)
        pA[i] = A + (size_t)(mi * 8 + wm * 4 + i) * 65536 + wk * 512 + lane * 8;
    // B frags: chunk (kc = kt*8+wk, cb = ci*4+j)
    const __bf16* pB[4];
#pragma unroll
    for (int j = 0; j < 4; ++j)
        pB[j] = Bp + (size_t)(wk * 32 + (ci * 4 + j)) * 512 + lane * 8;

    f32x4 acc[4][4] = {};

#pragma unroll 4
    for (int kt = 0; kt < 16; ++kt) {
        bf16x8 af[4], bv[4];
#pragma unroll
        for (int i = 0; i < 4; ++i)
            af[i] = *(const bf16x8*)(pA[i] + kt * 4096);
#pragma unroll
        for (int j = 0; j < 4; ++j)
            bv[j] = *(const bf16x8*)(pB[j] + kt * 131072);
#pragma unroll
        for (int i = 0; i < 4; ++i)
#pragma unroll
            for (int j = 0; j < 4; ++j)
                acc[i][j] = __builtin_amdgcn_mfma_f32_16x16x32_bf16(
                    af[i], bv[j], acc[i][j], 0, 0, 0);
    }

    // slots: [8 wk][4 u] x 1KB = 32KB at 0; Ct[64][66] f32 at +32768.
    float* part = (float*)smem;
    float* Ct   = (float*)(smem + 32768);

    float accf[16];                      // MODE 2 fc1 accumulators (both halves)
    if (MODE == 2) {
#pragma unroll
        for (int b = 0; b < 16; ++b) accf[b] = 0.f;
    }

#pragma unroll 1
    for (int h = 0; h < 2; ++h) {
        // ---- 8-way k-reduce for half h (R17 structure; only wm==h writes) ----
#pragma unroll
        for (int r = 0; r < 4; ++r) {
            __syncthreads();             // slots free / prev-half Ct reads done
            if (wm == h) {
#pragma unroll
                for (int u = 0; u < 4; ++u)
                    *(f32x4*)(part + (wk * 4 + u) * 256 + lane * 4) = acc[r][u];
            }
            __syncthreads();
            if (wm == h && wk < 4) {     // wk reduces u=wk across 8 slots
                f32x4 fin = {};
#pragma unroll
                for (int sl = 0; sl < 8; ++sl)
                    fin += *(const f32x4*)(part + (sl * 4 + wk) * 256 + lane * 4);
                // C/D: col=lane&15, row=quad*4+reg (harness-verified)
#pragma unroll
                for (int rr = 0; rr < 4; ++rr)
                    Ct[(r * 16 + quad * 4 + rr) * 66 + wk * 16 + lr] = fin[rr];
            }
        }
        __syncthreads();                 // Ct complete for half h

        if (MODE == 0) {
            if (tx < 512) {              // 512 packed chunks for this half
                const int lp = tx & 63, cbl = (tx >> 6) & 3, kcl = tx >> 8;
                const int cl = cbl * 16 + (lp & 15);
                const float bf = ba[cl & 3];
                const int mb = kcl * 32 + ((lp >> 4) & 3) * 8;
                bf16x8 o;
#pragma unroll
                for (int j = 0; j < 8; ++j)
                    o[j] = (__bf16)fmaxf(Ct[(mb + j) * 66 + cl] + bf, 0.f);
                *(bf16x8*)(Op + ((size_t)((mi * 4 + h * 2 + kcl) * 32 +
                                          (ci * 4 + cbl)) * 64 + lp) * 8) = o;
            }
        } else if (MODE == 1) {
            if (tx < 512) {
                float W2l[16], W3l[12], bl2[4];
#pragma unroll
                for (int i = 0; i < 16; ++i) W2l[i] = Wa[i];
#pragma unroll
                for (int i = 0; i < 12; ++i) W3l[i] = Wb[i];
#pragma unroll
                for (int i = 0; i < 4; ++i) bl2[i] = ba[i];
                const int lp = tx & 63, cbl = (tx >> 6) & 3, kcl = tx >> 8;
                const int cl = cbl * 16 + (lp & 15);
                const int bloc = cl >> 2, f3 = cl & 3;
                const int mb = kcl * 32 + ((lp >> 4) & 3) * 8;
                bf16x8 o;
#pragma unroll
                for (int j = 0; j < 8; ++j) {
                    const float* row = &Ct[(mb + j) * 66 + bloc * 4];
                    float v = 0.f;
                    if (f3 < 3) {
#pragma unroll
                        for (int fo = 0; fo < 4; ++fo) {
                            const float tmp = fmaxf(row[0] * W2l[fo] + row[1] * W2l[4 + fo] +
                                                    row[2] * W2l[8 + fo] + row[3] * W2l[12 + fo] +
                                                    bl2[fo], 0.f);
                            const float w3a = W3l[fo * 3 + 0], w3b = W3l[fo * 3 + 1],
                                        w3c = W3l[fo * 3 + 2];
                            v += tmp * (f3 == 0 ? w3a : (f3 == 1 ? w3b : w3c));
                        }
                    }
                    o[j] = (__bf16)v;    // f3==3 -> 0 pad column
                }
                *(bf16x8*)(Op + ((size_t)((mi * 4 + h * 2 + kcl) * 32 +
                                          (ci * 4 + cbl)) * 64 + lp) * 8) = o;
            }
        } else {
            // fc1 partial: wave handles 4 nodes of this half; lane=j (0..53);
            // 16 batches (ci*16..+15). Ct reads are same-address broadcasts.
            const float b30 = ba[0], b31 = ba[1], b32 = ba[2];
            if (lane < 54) {
                for (int nn = 0; nn < 4; ++nn) {
                    const int nl = wave * 4 + nn;            // 0..63 in half
                    const int ng = m0 + h * 64 + nl;         // global node
#pragma unroll
                    for (int f = 0; f < 3; ++f) {
                        const float w = Wa[((size_t)ng * 3 + f) * 54 + lane];
                        const float bf = (f == 0) ? b30 : (f == 1 ? b31 : b32);
#pragma unroll
                        for (int b = 0; b < 16; ++b) {
                            const float r = fmaxf(Ct[nl * 66 + b * 4 + f] + bf, 0.f);
                            accf[b] += r * w;
                        }
                    }
                }
            }
        }
    }

    if (MODE == 2) {
        // ---- 16-wave tree reduce of accf -> atomics (reuses 32KB slot region) ----
        float* red = part;               // [8][16][64] f32 = 32KB
        __syncthreads();                 // prior slot/Ct traffic done
        if (wave >= 8) {
#pragma unroll
            for (int b = 0; b < 16; ++b)
                red[((wave - 8) * 16 + b) * 64 + lane] = accf[b];
        }
        __syncthreads();
        if (wave < 8) {
#pragma unroll
            for (int b = 0; b < 16; ++b)
                accf[b] += red[(wave * 16 + b) * 64 + lane];
        }
        __syncthreads();
        if (wave < 8) {
#pragma unroll
            for (int b = 0; b < 16; ++b)
                red[(wave * 16 + b) * 64 + lane] = accf[b];
        }
        __syncthreads();
        if (wave == 0 && lane < 54) {
            for (int b = 0; b < 16; ++b) {
                float s2 = 0.f;
#pragma unroll
                for (int w8 = 0; w8 < 8; ++w8)
                    s2 += red[(w8 * 16 + b) * 64 + lane];
                atomicAdd(&hidOut[(ci * 16 + b) * 54 + lane], s2);
            }
        }
    }
}

// out[b][a] = sum_j relu(hid_acc[b][j]+bfc[j]) * Wout[j][a] + bout[a]
__global__ __launch_bounds__(256) void fc2_k(const float* __restrict__ hid_acc,
                                             const float* __restrict__ bfc,
                                             const float* __restrict__ Wout,
                                             const float* __restrict__ bout,
                                             float* __restrict__ out) {
    const int tx = threadIdx.x;
    const int a  = blockIdx.x * 256 + tx;
    const int b0 = blockIdx.y * 4;
    __shared__ float hs[4 * 54];
    if (tx < 216) {
        const int j = tx % 54;
        hs[tx] = fmaxf(hid_acc[b0 * 54 + tx] + bfc[j], 0.f);
    }
    __syncthreads();
    float a0 = 0.f, a1 = 0.f, a2 = 0.f, a3 = 0.f;
    for (int j = 0; j < 54; ++j) {
        float w = Wout[(size_t)j * N_NODE + a];
        a0 += hs[0 * 54 + j] * w;
        a1 += hs[1 * 54 + j] * w;
        a2 += hs[2 * 54 + j] * w;
        a3 += hs[3 * 54 + j] * w;
    }
    float bo = bout[a];
    out[(size_t)(b0 + 0) * N_NODE + a] = a0 + bo;
    out[(size_t)(b0 + 1) * N_NODE + a] = a1 + bo;
    out[(size_t)(b0 + 2) * N_NODE + a] = a2 + bo;
    out[(size_t)(b0 + 3) * N_NODE + a] = a3 + bo;
}

extern "C" void kernel_launch(void* const* d_in, const int* in_sizes, int n_in,
                              void* d_out, int out_size, void* d_ws, size_t ws_size,
                              hipStream_t stream) {
    const float* X    = (const float*)d_in[0];
    const float* adj  = (const float*)d_in[1];
    const float* W1   = (const float*)d_in[2];
    const float* b1   = (const float*)d_in[3];
    const float* W2   = (const float*)d_in[4];
    const float* b2   = (const float*)d_in[5];
    const float* W3   = (const float*)d_in[6];
    const float* b3   = (const float*)d_in[7];
    const float* Wfc  = (const float*)d_in[8];
    const float* bfc  = (const float*)d_in[9];
    const float* Wout = (const float*)d_in[10];
    const float* bout = (const float*)d_in[11];
    float* out = (float*)d_out;

    // ws: adjB (A-pack) 32MB | G0 packed 4MB | H1 packed 4MB | H2g packed 4MB
    //   | hid [128][54]
    char* w = (char*)d_ws;
    __bf16* adjB = (__bf16*)w;
    __bf16* G0   = (__bf16*)(w + 33554432);
    __bf16* H1   = (__bf16*)(w + 33554432 + 4194304);
    __bf16* H2g  = (__bf16*)(w + 33554432 + 2 * 4194304);
    float*  hid  = (float*)(w + 33554432 + 3 * 4194304);

    prep_k<<<9243, 256, 0, stream>>>(adj, adjB, X, W1, G0, hid);

    // stage 1: H1 = relu(adj @ G0 + b1)            (W1 pre-applied in prep)
    gcn_k<0><<<256, 1024, 0, stream>>>(adjB, G0, nullptr, b1, nullptr, H1, nullptr);
    // stage 2: H2g = (relu(adj @ H1 @ W2 + b2)) @ W3, padded f=4
    gcn_k<1><<<256, 1024, 0, stream>>>(adjB, H1, W2, b2, W3, H2g, nullptr);
    // stage 3: fused  relu(adj @ H2g + b3)  +  fc1 partial sums -> hid
    gcn_k<2><<<256, 1024, 0, stream>>>(adjB, H2g, Wfc, b3, nullptr, nullptr, hid);

    // FC head tail
    fc2_k<<<dim3(16, 32), 256, 0, stream>>>(hid, bfc, Wout, bout, out);
}

// Round 13
// 244.468 us; speedup vs baseline: 1.0321x; 1.0321x over previous
//
#include <hip/hip_runtime.h>

// ---------------------------------------------------------------------------
// sxsGCN: h=[B=128,N=4096,3]; 3x { relu((adj@h)@W+b) }; then FC 12288->54->4096
// bf16 MFMA GEMMs adj[4096x4096] @ H[4096 x 512].
// R13: barrier-free GEMM, frag-packed operands, global->VGPR. R14: fc1 fused
//   into gcn<2>: 218us. R17: 64x64, 512thr 8-way k-slice, lb(512,4), 2 blk/CU
//   (4 waves/SIMD): 209us, NO spill (proven: no scratch signature).
// R18-R20: 128x64 @1024thr: toolchain pins VGPR=64 for 1024-thr workgroups
//   under lb(1024,4), lb(1024), AND amdgpu_waves_per_eu(4,4) -> acc spills
//   (81MB scratch/dispatch, 75us). 1024-thr path dead.
// R21: byte-cut experiment on the PROVEN 512-thr vehicle. 128x64 tile,
//   256 blocks x 512 thr = 8 waves (2 m-halves wm x 4 k-slices wk),
//   1 blk/CU = 2 waves/SIMD. Per-CU bytes 2MB -> 1.5MB (read-once).
//   Discriminates: occupancy 2->4 bought only 9% (R14->R17); byte model
//   (L1-fill wall) predicts -25%. K-loop = R13 addressing verbatim;
//   reduce = R13's 4-wave linear exchange per half (gated wm==h);
//   epilogue = R19 formulas; fc1 = 8-wave tree. LDS 49,664B (=R17).
// ---------------------------------------------------------------------------

typedef __bf16 bf16x8 __attribute__((ext_vector_type(8)));
typedef float  f32x4  __attribute__((ext_vector_type(4)));

#define N_NODE 4096
#define BATCH  128

// prep: [0,8192) adjB A-frag pack | [8192,9216) G0 B-frag pack = (X@W1)
//       | [9216,9243) zero hid
__global__ __launch_bounds__(256) void prep_k(const float* __restrict__ adj,
                                              __bf16* __restrict__ adjB,
                                              const float* __restrict__ X,
                                              const float* __restrict__ W1,
                                              __bf16* __restrict__ G0,
                                              float* __restrict__ hid_acc) {
    const int blk = blockIdx.x, tx = threadIdx.x;
    if (blk < 8192) {
        // A-frag pack: chunk g = (rb*128 + ka)*64 + lane holds
        // row = rb*16+(lane&15), k = ka*32+((lane>>4)&3)*8 .. +7
        const int g = blk * 256 + tx;
        const int lane = g & 63, ka = (g >> 6) & 127, rb = g >> 13;
        const int row = rb * 16 + (lane & 15);
        const int kb  = ka * 32 + ((lane >> 4) & 3) * 8;
        const float4* s = (const float4*)(adj + (size_t)row * 4096 + kb);
        float4 u = s[0];
        float4 v = s[1];
        bf16x8 o = { (__bf16)u.x, (__bf16)u.y, (__bf16)u.z, (__bf16)u.w,
                     (__bf16)v.x, (__bf16)v.y, (__bf16)v.z, (__bf16)v.w };
        *(bf16x8*)(adjB + (size_t)g * 8) = o;
    } else if (blk < 9216) {
        // B-frag pack: chunk g = (kc*32 + cb)*64 + lane holds
        // c = cb*16+(lane&15), m = kc*32+((lane>>4)&3)*8 .. +7
        const int g = (blk - 8192) * 256 + tx;
        const int lp = g & 63, cbg = (g >> 6) & 31, kc = g >> 11;
        const int c = cbg * 16 + (lp & 15);
        const int b = c >> 2, f = c & 3;
        const float w0 = W1[0 * 4 + f], w1 = W1[1 * 4 + f], w2 = W1[2 * 4 + f];
        const int mb = kc * 32 + ((lp >> 4) & 3) * 8;
        const float* Xb = X + (size_t)b * 12288 + (size_t)mb * 3;
        bf16x8 o;
#pragma unroll
        for (int j = 0; j < 8; ++j) {
            const float v = Xb[j * 3 + 0] * w0 + Xb[j * 3 + 1] * w1 + Xb[j * 3 + 2] * w2;
            o[j] = (__bf16)v;
        }
        *(bf16x8*)(G0 + (size_t)g * 8) = o;
    } else {
        const int i = (blk - 9216) * 256 + tx;
        if (i < BATCH * 54) hid_acc[i] = 0.f;
    }
}

// Fused GEMM + epilogue. Tile 128(M)x64(N), 512 threads = 8 waves:
// wm = wave>>2 owns rows [wm*64,+64), wk = wave&3 owns k-chunks ka=kt*4+wk
// (32 steps of BK=128), acc[4][4]. Both operands direct global->VGPR,
// frag-packed; no LDS/barriers in K-loop. Epilogue per half h: R13's 4-wave
// linear reduce among waves wm==h -> Ct[64][66] -> MODE output for the half.
//   MODE 0: relu(C+b1) -> packed bf16       MODE 1: (relu(C@W2+b2))@W3 packed
//   MODE 2: fused fc1: hid[b][j] += sum_{n,f} relu(C+b3)*Wfc (atomicAdd)
template <int MODE>
__global__ __launch_bounds__(512, 4) void gcn_k(const __bf16* __restrict__ A,
                                                const __bf16* __restrict__ Bp,
                                                const float* __restrict__ Wa,
                                                const float* __restrict__ ba,
                                                const float* __restrict__ Wb,
                                                __bf16* __restrict__ Op,
                                                float* __restrict__ hidOut) {
    __shared__ __align__(16) unsigned char smem[49664];
    const int tx = threadIdx.x;
    const int wave = tx >> 6, lane = tx & 63;
    const int wm = wave >> 2, wk = wave & 3;
    const int quad = lane >> 4, lr = lane & 15;

    const int l = blockIdx.x;
    const int xcd = l & 7, s = l >> 3;
    const int mi = xcd * 4 + (s & 3), ci = s >> 2;     // mi 0..31, ci 0..7
    const int m0 = mi * 128;

    // A frags: chunk (rb = mi*8 + wm*4 + i, ka = kt*4+wk)
    const __bf16* pA[4];
#pragma unroll
    for (int i = 0; i < 4; ++i)
        pA[i] = A + (size_t)(mi * 8 + wm * 4 + i) * 65536 + wk * 512 + lane * 8;
    // B frags: chunk (kc = kt*4+wk, cb = ci*4+j)
    const __bf16* pB[4];
#pragma unroll
    for (int j = 0; j < 4; ++j)
        pB[j] = Bp + (size_t)(wk * 32 + (ci * 4 + j)) * 512 + lane * 8;

    f32x4 acc[4][4] = {};

#pragma unroll 4
    for (int kt = 0; kt < 32; ++kt) {
        bf16x8 af[4], bv[4];
#pragma unroll
        for (int i = 0; i < 4; ++i)
            af[i] = *(const bf16x8*)(pA[i] + kt * 2048);
#pragma unroll
        for (int j = 0; j < 4; ++j)
            bv[j] = *(const bf16x8*)(pB[j] + kt * 65536);
#pragma unroll
        for (int i = 0; i < 4; ++i)
#pragma unroll
            for (int j = 0; j < 4; ++j)
                acc[i][j] = __builtin_amdgcn_mfma_f32_16x16x32_bf16(
                    af[i], bv[j], acc[i][j], 0, 0, 0);
    }

    // LDS: part 2 slots x 16KB at 0; Ct[64][66] f32 at +32768. = 49,664B.
    float* part = (float*)smem;
    float* Ct   = (float*)(smem + 32768);

    float accf[16];                      // MODE 2 fc1 accumulators (both halves)
    if (MODE == 2) {
#pragma unroll
        for (int b = 0; b < 16; ++b) accf[b] = 0.f;
    }

#pragma unroll 1
    for (int h = 0; h < 2; ++h) {
        // ---- R13 4-wave linear reduce among waves wm==h ----
        __syncthreads();                 // slots/Ct free from prev half
        const int sb = (wk >> 1) * 4096;
        if (wm == h && (wk & 1)) {       // wk 1,3 write
#pragma unroll
            for (int t = 0; t < 16; ++t)
                *(f32x4*)(part + sb + t * 256 + lane * 4) = acc[t >> 2][t & 3];
        }
        __syncthreads();
        if (wm == h && !(wk & 1)) {      // wk 0,2 add partner
#pragma unroll
            for (int t = 0; t < 16; ++t)
                acc[t >> 2][t & 3] += *(const f32x4*)(part + sb + t * 256 + lane * 4);
        }
        __syncthreads();
        if (wm == h && wk == 2) {        // wk 2 writes its sum
#pragma unroll
            for (int t = 0; t < 16; ++t)
                *(f32x4*)(part + t * 256 + lane * 4) = acc[t >> 2][t & 3];
        }
        __syncthreads();
        if (wm == h && wk == 0) {        // wk 0: full sum + transpose
#pragma unroll
            for (int t = 0; t < 16; ++t)
                acc[t >> 2][t & 3] += *(const f32x4*)(part + t * 256 + lane * 4);
            // C/D: col=lane&15, row=quad*4+reg (harness-verified)
#pragma unroll
            for (int i = 0; i < 4; ++i)
#pragma unroll
                for (int j = 0; j < 4; ++j)
#pragma unroll
                    for (int r = 0; r < 4; ++r)
                        Ct[(i * 16 + quad * 4 + r) * 66 + j * 16 + lr] = acc[i][j][r];
        }
        __syncthreads();                 // Ct complete for half h

        if (MODE == 0) {
            const int lp = tx & 63, cbl = (tx >> 6) & 3, kcl = tx >> 8;
            const int cl = cbl * 16 + (lp & 15);
            const float bf = ba[cl & 3];
            const int mb = kcl * 32 + ((lp >> 4) & 3) * 8;
            bf16x8 o;
#pragma unroll
            for (int j = 0; j < 8; ++j)
                o[j] = (__bf16)fmaxf(Ct[(mb + j) * 66 + cl] + bf, 0.f);
            *(bf16x8*)(Op + ((size_t)((mi * 4 + h * 2 + kcl) * 32 +
                                      (ci * 4 + cbl)) * 64 + lp) * 8) = o;
        } else if (MODE == 1) {
            float W2l[16], W3l[12], bl2[4];
#pragma unroll
            for (int i = 0; i < 16; ++i) W2l[i] = Wa[i];
#pragma unroll
            for (int i = 0; i < 12; ++i) W3l[i] = Wb[i];
#pragma unroll
            for (int i = 0; i < 4; ++i) bl2[i] = ba[i];
            const int lp = tx & 63, cbl = (tx >> 6) & 3, kcl = tx >> 8;
            const int cl = cbl * 16 + (lp & 15);
            const int bloc = cl >> 2, f3 = cl & 3;
            const int mb = kcl * 32 + ((lp >> 4) & 3) * 8;
            bf16x8 o;
#pragma unroll
            for (int j = 0; j < 8; ++j) {
                const float* row = &Ct[(mb + j) * 66 + bloc * 4];
                float v = 0.f;
                if (f3 < 3) {
#pragma unroll
                    for (int fo = 0; fo < 4; ++fo) {
                        const float tmp = fmaxf(row[0] * W2l[fo] + row[1] * W2l[4 + fo] +
                                                row[2] * W2l[8 + fo] + row[3] * W2l[12 + fo] +
                                                bl2[fo], 0.f);
                        const float w3a = W3l[fo * 3 + 0], w3b = W3l[fo * 3 + 1],
                                    w3c = W3l[fo * 3 + 2];
                        v += tmp * (f3 == 0 ? w3a : (f3 == 1 ? w3b : w3c));
                    }
                }
                o[j] = (__bf16)v;        // f3==3 -> 0 pad column
            }
            *(bf16x8*)(Op + ((size_t)((mi * 4 + h * 2 + kcl) * 32 +
                                      (ci * 4 + cbl)) * 64 + lp) * 8) = o;
        } else {
            // fc1 partial: wave handles 8 nodes of this half; lane=j (0..53);
            // 16 batches (ci*16..+15). Ct reads are same-address broadcasts.
            const float b30 = ba[0], b31 = ba[1], b32 = ba[2];
            if (lane < 54) {
                for (int nn = 0; nn < 8; ++nn) {
                    const int nl = wave * 8 + nn;            // 0..63 in half
                    const int ng = m0 + h * 64 + nl;         // global node
#pragma unroll
                    for (int f = 0; f < 3; ++f) {
                        const float w = Wa[((size_t)ng * 3 + f) * 54 + lane];
                        const float bf = (f == 0) ? b30 : (f == 1 ? b31 : b32);
#pragma unroll
                        for (int b = 0; b < 16; ++b) {
                            const float r = fmaxf(Ct[nl * 66 + b * 4 + f] + bf, 0.f);
                            accf[b] += r * w;
                        }
                    }
                }
            }
        }
    }

    if (MODE == 2) {
        // ---- 8-wave tree reduce of accf -> atomics (reuses slot region) ----
        float* red = part;               // [4][16][64] f32 = 16KB
        __syncthreads();                 // prior Ct/slot traffic done
        if (wave >= 4) {
#pragma unroll
            for (int b = 0; b < 16; ++b)
                red[((wave - 4) * 16 + b) * 64 + lane] = accf[b];
        }
        __syncthreads();
        if (wave < 4) {
#pragma unroll
            for (int b = 0; b < 16; ++b)
                accf[b] += red[(wave * 16 + b) * 64 + lane];
        }
        __syncthreads();
        if (wave < 4) {
#pragma unroll
            for (int b = 0; b < 16; ++b)
                red[(wave * 16 + b) * 64 + lane] = accf[b];
        }
        __syncthreads();
        if (wave == 0 && lane < 54) {
            for (int b = 0; b < 16; ++b) {
                const float s2 = red[(0 * 16 + b) * 64 + lane] +
                                 red[(1 * 16 + b) * 64 + lane] +
                                 red[(2 * 16 + b) * 64 + lane] +
                                 red[(3 * 16 + b) * 64 + lane];
                atomicAdd(&hidOut[(ci * 16 + b) * 54 + lane], s2);
            }
        }
    }
}

// out[b][a] = sum_j relu(hid_acc[b][j]+bfc[j]) * Wout[j][a] + bout[a]
__global__ __launch_bounds__(256) void fc2_k(const float* __restrict__ hid_acc,
                                             const float* __restrict__ bfc,
                                             const float* __restrict__ Wout,
                                             const float* __restrict__ bout,
                                             float* __restrict__ out) {
    const int tx = threadIdx.x;
    const int a  = blockIdx.x * 256 + tx;
    const int b0 = blockIdx.y * 4;
    __shared__ float hs[4 * 54];
    if (tx < 216) {
        const int j = tx % 54;
        hs[tx] = fmaxf(hid_acc[b0 * 54 + tx] + bfc[j], 0.f);
    }
    __syncthreads();
    float a0 = 0.f, a1 = 0.f, a2 = 0.f, a3 = 0.f;
    for (int j = 0; j < 54; ++j) {
        float w = Wout[(size_t)j * N_NODE + a];
        a0 += hs[0 * 54 + j] * w;
        a1 += hs[1 * 54 + j] * w;
        a2 += hs[2 * 54 + j] * w;
        a3 += hs[3 * 54 + j] * w;
    }
    float bo = bout[a];
    out[(size_t)(b0 + 0) * N_NODE + a] = a0 + bo;
    out[(size_t)(b0 + 1) * N_NODE + a] = a1 + bo;
    out[(size_t)(b0 + 2) * N_NODE + a] = a2 + bo;
    out[(size_t)(b0 + 3) * N_NODE + a] = a3 + bo;
}

extern "C" void kernel_launch(void* const* d_in, const int* in_sizes, int n_in,
                              void* d_out, int out_size, void* d_ws, size_t ws_size,
                              hipStream_t stream) {
    const float* X    = (const float*)d_in[0];
    const float* adj  = (const float*)d_in[1];
    const float* W1   = (const float*)d_in[2];
    const float* b1   = (const float*)d_in[3];
    const float* W2   = (const float*)d_in[4];
    const float* b2   = (const float*)d_in[5];
    const float* W3   = (const float*)d_in[6];
    const float* b3   = (const float*)d_in[7];
    const float* Wfc  = (const float*)d_in[8];
    const float* bfc  = (const float*)d_in[9];
    const float* Wout = (const float*)d_in[10];
    const float* bout = (const float*)d_in[11];
    float* out = (float*)d_out;

    // ws: adjB (A-pack) 32MB | G0 packed 4MB | H1 packed 4MB | H2g packed 4MB
    //   | hid [128][54]
    char* w = (char*)d_ws;
    __bf16* adjB = (__bf16*)w;
    __bf16* G0   = (__bf16*)(w + 33554432);
    __bf16* H1   = (__bf16*)(w + 33554432 + 4194304);
    __bf16* H2g  = (__bf16*)(w + 33554432 + 2 * 4194304);
    float*  hid  = (float*)(w + 33554432 + 3 * 4194304);

    prep_k<<<9243, 256, 0, stream>>>(adj, adjB, X, W1, G0, hid);

    // stage 1: H1 = relu(adj @ G0 + b1)            (W1 pre-applied in prep)
    gcn_k<0><<<256, 512, 0, stream>>>(adjB, G0, nullptr, b1, nullptr, H1, nullptr);
    // stage 2: H2g = (relu(adj @ H1 @ W2 + b2)) @ W3, padded f=4
    gcn_k<1><<<256, 512, 0, stream>>>(adjB, H1, W2, b2, W3, H2g, nullptr);
    // stage 3: fused  relu(adj @ H2g + b3)  +  fc1 partial sums -> hid
    gcn_k<2><<<256, 512, 0, stream>>>(adjB, H2g, Wfc, b3, nullptr, nullptr, hid);

    // FC head tail
    fc2_k<<<dim3(16, 32), 256, 0, stream>>>(hid, bfc, Wout, bout, out);
}

// Round 14
// 206.931 us; speedup vs baseline: 1.2193x; 1.1814x over previous
//
#include <hip/hip_runtime.h>

// ---------------------------------------------------------------------------
// sxsGCN: h=[B=128,N=4096,3]; 3x { relu((adj@h)@W+b) }; then FC 12288->54->4096
// bf16 MFMA GEMMs adj[4096x4096] @ H[4096 x 512].
// FINAL MODEL (R9-R21 data): per-CU L2->CU delivery plateaus at ~22B/cy for
//   this streaming pattern at >=2 blk/CU (drops to ~14 at 1 blk/CU). L2
//   traffic is fixed at 512MB/GEMM by tiling algebra (A x8 + B x64 re-reads)
//   -> ~38us/GEMM floor, measured invariant across 6 schedules (35-41us).
//   Byte-cut tiles (128x64) force 1 blk/CU -> worse (R21: 61us). Fill 41us
//   harness-fixed; prep ~16us at HBM floor; fc tail ~8us.
// R22: revert to champion R17 (209.2us verified) + T5 s_setprio around the
//   MFMA cluster (valid regime here: barrier-free independent waves = the
//   m191 +4-7% case, NOT the m190 lockstep null case). Single cheap tweak.
//   R17 structure: 64x64 tiles, 512 blocks x 512 thr = 8 k-slice waves
//   (ka = kt*8+wave, 16 steps of BK=256), acc[4][4], both operands
//   frag-packed global->VGPR, no LDS/barriers in K-loop; 4-round static
//   slot reduce -> Ct[64][66]; fc1 fused into MODE 2 (atomicAdd).
// ---------------------------------------------------------------------------

typedef __bf16 bf16x8 __attribute__((ext_vector_type(8)));
typedef float  f32x4  __attribute__((ext_vector_type(4)));

#define N_NODE 4096
#define BATCH  128

// prep: [0,8192) adjB A-frag pack | [8192,9216) G0 B-frag pack = (X@W1)
//       | [9216,9243) zero hid
__global__ __launch_bounds__(256) void prep_k(const float* __restrict__ adj,
                                              __bf16* __restrict__ adjB,
                                              const float* __restrict__ X,
                                              const float* __restrict__ W1,
                                              __bf16* __restrict__ G0,
                                              float* __restrict__ hid_acc) {
    const int blk = blockIdx.x, tx = threadIdx.x;
    if (blk < 8192) {
        // A-frag pack: chunk g = (rb*128 + ka)*64 + lane holds
        // row = rb*16+(lane&15), k = ka*32+((lane>>4)&3)*8 .. +7
        const int g = blk * 256 + tx;
        const int lane = g & 63, ka = (g >> 6) & 127, rb = g >> 13;
        const int row = rb * 16 + (lane & 15);
        const int kb  = ka * 32 + ((lane >> 4) & 3) * 8;
        const float4* s = (const float4*)(adj + (size_t)row * 4096 + kb);
        float4 u = s[0];
        float4 v = s[1];
        bf16x8 o = { (__bf16)u.x, (__bf16)u.y, (__bf16)u.z, (__bf16)u.w,
                     (__bf16)v.x, (__bf16)v.y, (__bf16)v.z, (__bf16)v.w };
        *(bf16x8*)(adjB + (size_t)g * 8) = o;
    } else if (blk < 9216) {
        // B-frag pack: chunk g = (kc*32 + cb)*64 + lane holds
        // c = cb*16+(lane&15), m = kc*32+((lane>>4)&3)*8 .. +7
        const int g = (blk - 8192) * 256 + tx;
        const int lp = g & 63, cbg = (g >> 6) & 31, kc = g >> 11;
        const int c = cbg * 16 + (lp & 15);
        const int b = c >> 2, f = c & 3;
        const float w0 = W1[0 * 4 + f], w1 = W1[1 * 4 + f], w2 = W1[2 * 4 + f];
        const int mb = kc * 32 + ((lp >> 4) & 3) * 8;
        const float* Xb = X + (size_t)b * 12288 + (size_t)mb * 3;
        bf16x8 o;
#pragma unroll
        for (int j = 0; j < 8; ++j) {
            const float v = Xb[j * 3 + 0] * w0 + Xb[j * 3 + 1] * w1 + Xb[j * 3 + 2] * w2;
            o[j] = (__bf16)v;
        }
        *(bf16x8*)(G0 + (size_t)g * 8) = o;
    } else {
        const int i = (blk - 9216) * 256 + tx;
        if (i < BATCH * 54) hid_acc[i] = 0.f;
    }
}

// Fused GEMM + epilogue. Tile 64(M)x64(N), 512 threads = 8 waves; wave owns
// k-chunks ka = kt*8+wave (16 steps of BK=256), acc[4][4].
// Both operands direct global->VGPR, frag-packed; no LDS/barriers in K-loop.
// Epilogue: 4 static rounds of 8-slot exchange -> Ct[64][66]; then:
//   MODE 0: relu(C+b1) -> packed bf16       MODE 1: (relu(C@W2+b2))@W3 packed
//   MODE 2: fused fc1: hid[b][j] += sum_{n,f} relu(C+b3)*Wfc (atomicAdd)
template <int MODE>
__global__ __launch_bounds__(512, 4) void gcn_k(const __bf16* __restrict__ A,
                                                const __bf16* __restrict__ Bp,
                                                const float* __restrict__ Wa,
                                                const float* __restrict__ ba,
                                                const float* __restrict__ Wb,
                                                __bf16* __restrict__ Op,
                                                float* __restrict__ hidOut) {
    __shared__ __align__(16) unsigned char smem[49664];
    const int tx = threadIdx.x;
    const int wave = tx >> 6, lane = tx & 63;
    const int quad = lane >> 4, lr = lane & 15;

    const int l = blockIdx.x;
    const int xcd = l & 7, s = l >> 3;
    const int mi = xcd * 8 + (s & 7), ci = s >> 3;     // mi 0..63, ci 0..7
    const int m0 = mi * 64;

    // A frags: chunk (rb = mi*4+i, ka = kt*8+wave)
    const __bf16* pA[4];
#pragma unroll
    for (int i = 0; i < 4; ++i)
        pA[i] = A + (size_t)(mi * 4 + i) * 65536 + wave * 512 + lane * 8;
    // B frags: chunk (kc = kt*8+wave, cb = ci*4+j)
    const __bf16* pB[4];
#pragma unroll
    for (int j = 0; j < 4; ++j)
        pB[j] = Bp + (size_t)(wave * 32 + (ci * 4 + j)) * 512 + lane * 8;

    f32x4 acc[4][4] = {};

#pragma unroll 4
    for (int kt = 0; kt < 16; ++kt) {
        bf16x8 af[4], bv[4];
#pragma unroll
        for (int i = 0; i < 4; ++i)
            af[i] = *(const bf16x8*)(pA[i] + kt * 4096);
#pragma unroll
        for (int j = 0; j < 4; ++j)
            bv[j] = *(const bf16x8*)(pB[j] + kt * 131072);
        __builtin_amdgcn_s_setprio(1);   // T5: free-running waves regime
#pragma unroll
        for (int i = 0; i < 4; ++i)
#pragma unroll
            for (int j = 0; j < 4; ++j)
                acc[i][j] = __builtin_amdgcn_mfma_f32_16x16x32_bf16(
                    af[i], bv[j], acc[i][j], 0, 0, 0);
        __builtin_amdgcn_s_setprio(0);
    }

    // ---- 8-way cross-wave k-reduce: 4 static rounds ----
    // slots: [8 waves][4 u] x (64 lanes x f32x4 = 256 floats = 1KB) = 32KB;
    // Ct[64][66] f32 at +32768 (16,896B). Total = 49,664B.
    float* part = (float*)smem;
    float* Ct   = (float*)(smem + 32768);
#pragma unroll
    for (int r = 0; r < 4; ++r) {
        __syncthreads();                 // slots free (prev round consumed)
#pragma unroll
        for (int u = 0; u < 4; ++u)
            *(f32x4*)(part + (wave * 4 + u) * 256 + lane * 4) = acc[r][u];
        __syncthreads();
        if (wave < 4) {                  // wave w reduces u=w across 8 slots
            f32x4 fin = {};
#pragma unroll
            for (int sl = 0; sl < 8; ++sl)
                fin += *(const f32x4*)(part + (sl * 4 + wave) * 256 + lane * 4);
            // C/D: col=lane&15, row=quad*4+reg (harness-verified)
#pragma unroll
            for (int rr = 0; rr < 4; ++rr)
                Ct[(r * 16 + quad * 4 + rr) * 66 + wave * 16 + lr] = fin[rr];
        }
    }
    __syncthreads();                     // Ct complete

    if (MODE == 0) {
        const int g2 = tx;               // 512 packed chunks/block, one pass
        const int lp = g2 & 63, cbl = (g2 >> 6) & 3, kcl = g2 >> 8;
        const int cl = cbl * 16 + (lp & 15);
        const float bf = ba[cl & 3];
        const int mb = kcl * 32 + ((lp >> 4) & 3) * 8;
        bf16x8 o;
#pragma unroll
        for (int j = 0; j < 8; ++j)
            o[j] = (__bf16)fmaxf(Ct[(mb + j) * 66 + cl] + bf, 0.f);
        *(bf16x8*)(Op + ((size_t)((mi * 2 + kcl) * 32 + (ci * 4 + cbl)) * 64 + lp) * 8) = o;
    } else if (MODE == 1) {
        float W2l[16], W3l[12], bl2[4];
#pragma unroll
        for (int i = 0; i < 16; ++i) W2l[i] = Wa[i];
#pragma unroll
        for (int i = 0; i < 12; ++i) W3l[i] = Wb[i];
#pragma unroll
        for (int i = 0; i < 4; ++i) bl2[i] = ba[i];
        const int g2 = tx;
        const int lp = g2 & 63, cbl = (g2 >> 6) & 3, kcl = g2 >> 8;
        const int cl = cbl * 16 + (lp & 15);
        const int bloc = cl >> 2, f3 = cl & 3;
        const int mb = kcl * 32 + ((lp >> 4) & 3) * 8;
        bf16x8 o;
#pragma unroll
        for (int j = 0; j < 8; ++j) {
            const float* row = &Ct[(mb + j) * 66 + bloc * 4];
            float v = 0.f;
            if (f3 < 3) {
#pragma unroll
                for (int fo = 0; fo < 4; ++fo) {
                    const float tmp = fmaxf(row[0] * W2l[fo] + row[1] * W2l[4 + fo] +
                                            row[2] * W2l[8 + fo] + row[3] * W2l[12 + fo] +
                                            bl2[fo], 0.f);
                    const float w3a = W3l[fo * 3 + 0], w3b = W3l[fo * 3 + 1],
                                w3c = W3l[fo * 3 + 2];
                    v += tmp * (f3 == 0 ? w3a : (f3 == 1 ? w3b : w3c));
                }
            }
            o[j] = (__bf16)v;            // f3==3 -> 0 pad column
        }
        *(bf16x8*)(Op + ((size_t)((mi * 2 + kcl) * 32 + (ci * 4 + cbl)) * 64 + lp) * 8) = o;
    } else {
        // ---- fused fc1: block owns nodes m0..m0+63, batches ci*16..+15.
        // wave handles nodes wave*8..+7; lane=j (0..53); 16 batch-accs.
        // red [8][16][64] f32 = 32KB reuses the slot region (rounds done).
        float* red = part;
        const float b30 = ba[0], b31 = ba[1], b32 = ba[2];
        float accf[16];
#pragma unroll
        for (int b = 0; b < 16; ++b) accf[b] = 0.f;
        if (lane < 54) {
            for (int nn = 0; nn < 8; ++nn) {
                const int n = wave * 8 + nn;
#pragma unroll
                for (int f = 0; f < 3; ++f) {
                    const float w = Wa[((size_t)(m0 + n) * 3 + f) * 54 + lane];
                    const float bf = (f == 0) ? b30 : (f == 1 ? b31 : b32);
#pragma unroll
                    for (int b = 0; b < 16; ++b) {
                        const float r = fmaxf(Ct[n * 66 + b * 4 + f] + bf, 0.f);
                        accf[b] += r * w;
                    }
                }
            }
        }
#pragma unroll
        for (int b = 0; b < 16; ++b)
            red[(wave * 16 + b) * 64 + lane] = accf[b];
        __syncthreads();
        if (wave == 0 && lane < 54) {
            for (int b = 0; b < 16; ++b) {
                float s2 = 0.f;
#pragma unroll
                for (int w8 = 0; w8 < 8; ++w8)
                    s2 += red[(w8 * 16 + b) * 64 + lane];
                atomicAdd(&hidOut[(ci * 16 + b) * 54 + lane], s2);
            }
        }
    }
}

// out[b][a] = sum_j relu(hid_acc[b][j]+bfc[j]) * Wout[j][a] + bout[a]
__global__ __launch_bounds__(256) void fc2_k(const float* __restrict__ hid_acc,
                                             const float* __restrict__ bfc,
                                             const float* __restrict__ Wout,
                                             const float* __restrict__ bout,
                                             float* __restrict__ out) {
    const int tx = threadIdx.x;
    const int a  = blockIdx.x * 256 + tx;
    const int b0 = blockIdx.y * 4;
    __shared__ float hs[4 * 54];
    if (tx < 216) {
        const int j = tx % 54;
        hs[tx] = fmaxf(hid_acc[b0 * 54 + tx] + bfc[j], 0.f);
    }
    __syncthreads();
    float a0 = 0.f, a1 = 0.f, a2 = 0.f, a3 = 0.f;
    for (int j = 0; j < 54; ++j) {
        float w = Wout[(size_t)j * N_NODE + a];
        a0 += hs[0 * 54 + j] * w;
        a1 += hs[1 * 54 + j] * w;
        a2 += hs[2 * 54 + j] * w;
        a3 += hs[3 * 54 + j] * w;
    }
    float bo = bout[a];
    out[(size_t)(b0 + 0) * N_NODE + a] = a0 + bo;
    out[(size_t)(b0 + 1) * N_NODE + a] = a1 + bo;
    out[(size_t)(b0 + 2) * N_NODE + a] = a2 + bo;
    out[(size_t)(b0 + 3) * N_NODE + a] = a3 + bo;
}

extern "C" void kernel_launch(void* const* d_in, const int* in_sizes, int n_in,
                              void* d_out, int out_size, void* d_ws, size_t ws_size,
                              hipStream_t stream) {
    const float* X    = (const float*)d_in[0];
    const float* adj  = (const float*)d_in[1];
    const float* W1   = (const float*)d_in[2];
    const float* b1   = (const float*)d_in[3];
    const float* W2   = (const float*)d_in[4];
    const float* b2   = (const float*)d_in[5];
    const float* W3   = (const float*)d_in[6];
    const float* b3   = (const float*)d_in[7];
    const float* Wfc  = (const float*)d_in[8];
    const float* bfc  = (const float*)d_in[9];
    const float* Wout = (const float*)d_in[10];
    const float* bout = (const float*)d_in[11];
    float* out = (float*)d_out;

    // ws: adjB (A-pack) 32MB | G0 packed 4MB | H1 packed 4MB | H2g packed 4MB
    //   | hid [128][54]
    char* w = (char*)d_ws;
    __bf16* adjB = (__bf16*)w;
    __bf16* G0   = (__bf16*)(w + 33554432);
    __bf16* H1   = (__bf16*)(w + 33554432 + 4194304);
    __bf16* H2g  = (__bf16*)(w + 33554432 + 2 * 4194304);
    float*  hid  = (float*)(w + 33554432 + 3 * 4194304);

    prep_k<<<9243, 256, 0, stream>>>(adj, adjB, X, W1, G0, hid);

    // stage 1: H1 = relu(adj @ G0 + b1)            (W1 pre-applied in prep)
    gcn_k<0><<<512, 512, 0, stream>>>(adjB, G0, nullptr, b1, nullptr, H1, nullptr);
    // stage 2: H2g = (relu(adj @ H1 @ W2 + b2)) @ W3, padded f=4
    gcn_k<1><<<512, 512, 0, stream>>>(adjB, H1, W2, b2, W3, H2g, nullptr);
    // stage 3: fused  relu(adj @ H2g + b3)  +  fc1 partial sums -> hid
    gcn_k<2><<<512, 512, 0, stream>>>(adjB, H2g, Wfc, b3, nullptr, nullptr, hid);

    // FC head tail
    fc2_k<<<dim3(16, 32), 256, 0, stream>>>(hid, bfc, Wout, bout, out);
}